// Round 1
// baseline (863.332 us; speedup 1.0000x reference)
//
#include <hip/hip_runtime.h>

#define N_NODES 50000
#define N_EDGES 800000
#define D 128
#define C_OUT 10
#define BN_EPS 1e-5f

// ---------------- CSR build ----------------

__global__ void k_init(int* deg, float* sums) {
    int i = blockIdx.x * blockDim.x + threadIdx.x;
    if (i < N_NODES) deg[i] = 1;          // self loop contributes 1 to in-degree
    if (i < 768) sums[i] = 0.0f;          // 3 layers x (sum[128] | sumsq[128])
}

__global__ void k_count(const int* __restrict__ col, int* __restrict__ deg) {
    int e = blockIdx.x * blockDim.x + threadIdx.x;
    if (e < N_EDGES) atomicAdd(&deg[col[e]], 1);
}

__global__ void k_dinv(const int* __restrict__ deg, float* __restrict__ dinv) {
    int i = blockIdx.x * blockDim.x + threadIdx.x;
    if (i < N_NODES) dinv[i] = rsqrtf((float)deg[i]);  // deg >= 1 always
}

// single-block exclusive scan over deg[N] -> offsets[N+1], also init cursor
__global__ void k_scan(const int* __restrict__ deg, int* __restrict__ offsets,
                       int* __restrict__ cursor) {
    __shared__ int sm[1024];
    int tid = threadIdx.x;
    int carry = 0;
    const int chunks = (N_NODES + 1023) / 1024;
    for (int ch = 0; ch < chunks; ++ch) {
        int i = ch * 1024 + tid;
        int v = (i < N_NODES) ? deg[i] : 0;
        sm[tid] = v;
        __syncthreads();
        for (int off = 1; off < 1024; off <<= 1) {
            int t = (tid >= off) ? sm[tid - off] : 0;
            __syncthreads();
            sm[tid] += t;
            __syncthreads();
        }
        int incl = sm[tid];
        int total = sm[1023];
        if (i < N_NODES) {
            int excl = carry + incl - v;
            offsets[i] = excl;
            cursor[i] = excl;
        }
        carry += total;
        __syncthreads();  // protect sm before next chunk overwrites
    }
    if (tid == 0) offsets[N_NODES] = carry;  // == N_EDGES + N_NODES
}

__global__ void k_scatter(const int* __restrict__ ei, int* __restrict__ cursor,
                          int* __restrict__ csr_src) {
    int idx = blockIdx.x * blockDim.x + threadIdx.x;
    const int total = N_EDGES + N_NODES;
    if (idx >= total) return;
    int s, d;
    if (idx < N_EDGES) { s = ei[idx]; d = ei[N_EDGES + idx]; }  // row -> col
    else { s = idx - N_EDGES; d = s; }                           // self loop
    int p = atomicAdd(&cursor[d], 1);
    csr_src[p] = s;
}

// ---------------- GEMM: C[M,128] = A[M,128] @ W[128,128] (fp32) ----------------
// 64-row tile per block, K split in 2 chunks of 64; LDS = 17.4KB A + 32KB W < 64KB.

__global__ __launch_bounds__(256) void k_gemm(const float* __restrict__ A,
                                              const float* __restrict__ W,
                                              float* __restrict__ Cm) {
    __shared__ float As[64 * 68];    // 64 rows x 64 k, pad stride 68 (bank-safe)
    __shared__ float Ws[64 * 128];   // 64 k x 128 cols
    int tid = threadIdx.x;
    int row0 = blockIdx.x * 64;

    const float4* A4 = (const float4*)A;
    const float4* W4 = (const float4*)W;
    float4* Ws4 = (float4*)Ws;

    int tc = (tid & 15) * 8;   // 16 col-groups of 8
    int tr = (tid >> 4) * 4;   // 16 row-groups of 4

    float acc[4][8];
#pragma unroll
    for (int i = 0; i < 4; ++i)
#pragma unroll
        for (int j = 0; j < 8; ++j) acc[i][j] = 0.f;

    for (int kc = 0; kc < 2; ++kc) {
        // stage W chunk: rows [kc*64, kc*64+64), contiguous 8192 floats
#pragma unroll
        for (int it = 0; it < 8; ++it)
            Ws4[it * 256 + tid] = W4[kc * 2048 + it * 256 + tid];
        // stage A chunk: 64 rows x 64 cols
#pragma unroll
        for (int it = 0; it < 4; ++it) {
            int f4 = it * 256 + tid;     // 0..1023
            int r = f4 >> 4;             // 16 float4 per row
            int c4 = f4 & 15;
            float4 v = make_float4(0.f, 0.f, 0.f, 0.f);
            int gr = row0 + r;
            if (gr < N_NODES) v = A4[(size_t)gr * 32 + kc * 16 + c4];
            *(float4*)&As[r * 68 + c4 * 4] = v;
        }
        __syncthreads();
#pragma unroll 4
        for (int k = 0; k < 64; ++k) {
            float a0 = As[(tr + 0) * 68 + k];
            float a1 = As[(tr + 1) * 68 + k];
            float a2 = As[(tr + 2) * 68 + k];
            float a3 = As[(tr + 3) * 68 + k];
            float4 b0 = *(float4*)&Ws[k * 128 + tc];
            float4 b1 = *(float4*)&Ws[k * 128 + tc + 4];
            float a[4] = {a0, a1, a2, a3};
            float b[8] = {b0.x, b0.y, b0.z, b0.w, b1.x, b1.y, b1.z, b1.w};
#pragma unroll
            for (int i = 0; i < 4; ++i)
#pragma unroll
                for (int j = 0; j < 8; ++j) acc[i][j] += a[i] * b[j];
        }
        __syncthreads();
    }

#pragma unroll
    for (int i = 0; i < 4; ++i) {
        int r = row0 + tr + i;
        if (r < N_NODES) {
            float4 o0 = make_float4(acc[i][0], acc[i][1], acc[i][2], acc[i][3]);
            float4 o1 = make_float4(acc[i][4], acc[i][5], acc[i][6], acc[i][7]);
            *(float4*)&Cm[(size_t)r * 128 + tc] = o0;
            *(float4*)&Cm[(size_t)r * 128 + tc + 4] = o1;
        }
    }
}

// ---------------- Aggregation: one wave per node, float2/lane ----------------

__global__ void k_agg(const float* __restrict__ hl, const int* __restrict__ csr_src,
                      const int* __restrict__ offsets, const float* __restrict__ dinv,
                      float* __restrict__ agg) {
    int wave = (int)((blockIdx.x * blockDim.x + threadIdx.x) >> 6);
    int lane = threadIdx.x & 63;
    if (wave >= N_NODES) return;
    int beg = offsets[wave], end = offsets[wave + 1];
    float ax = 0.f, ay = 0.f;
    for (int e = beg; e < end; ++e) {
        int j = csr_src[e];
        float w = dinv[j];
        float2 v = *(const float2*)&hl[(size_t)j * 128 + lane * 2];
        ax += v.x * w;
        ay += v.y * w;
    }
    float di = dinv[wave];
    *(float2*)&agg[(size_t)wave * 128 + lane * 2] = make_float2(ax * di, ay * di);
}

// ---------------- BN ----------------

__global__ void k_bn_stats(const float* __restrict__ agg, float* __restrict__ sums) {
    __shared__ float sm[256];
    int tid = threadIdx.x;
    int c = tid & 127;
    float s = 0.f, q = 0.f;
    for (int r = blockIdx.x * 2 + (tid >> 7); r < N_NODES; r += gridDim.x * 2) {
        float v = agg[(size_t)r * 128 + c];
        s += v;
        q += v * v;
    }
    sm[tid] = s;
    __syncthreads();
    if (tid < 128) atomicAdd(&sums[c], sm[tid] + sm[tid + 128]);
    __syncthreads();
    sm[tid] = q;
    __syncthreads();
    if (tid < 128) atomicAdd(&sums[128 + c], sm[tid] + sm[tid + 128]);
}

__global__ void k_bn_finalize(const float* __restrict__ sums, const float* __restrict__ g,
                              const float* __restrict__ be, float* __restrict__ sc,
                              float* __restrict__ sh) {
    int c = threadIdx.x;
    if (c < 128) {
        float mean = sums[c] / (float)N_NODES;
        float var = sums[128 + c] / (float)N_NODES - mean * mean;
        var = fmaxf(var, 0.f);
        float s = g[c] * rsqrtf(var + BN_EPS);
        sc[c] = s;
        sh[c] = be[c] - mean * s;
    }
}

__global__ void k_bn_apply(float* __restrict__ buf, const float* __restrict__ sc,
                           const float* __restrict__ sh) {
    int idx = blockIdx.x * blockDim.x + threadIdx.x;  // float4 index
    const int total = N_NODES * 32;
    for (; idx < total; idx += gridDim.x * blockDim.x) {
        float4 v = ((float4*)buf)[idx];
        int c4 = idx & 31;
        float4 s = ((const float4*)sc)[c4];
        float4 t = ((const float4*)sh)[c4];
        v.x = fmaxf(v.x * s.x + t.x, 0.f);
        v.y = fmaxf(v.y * s.y + t.y, 0.f);
        v.z = fmaxf(v.z * s.z + t.z, 0.f);
        v.w = fmaxf(v.w * s.w + t.w, 0.f);
        ((float4*)buf)[idx] = v;
    }
}

// ---------------- Final readout partial: out += h_k @ Wf[base:base+128, :] ----------------

__global__ void k_out(const float* __restrict__ h, const float* __restrict__ Wf,
                      const float* __restrict__ bf, float* __restrict__ out,
                      int base, int addBias) {
    __shared__ float Wl[128 * C_OUT];  // 5KB slice
    int tid = threadIdx.x;
    for (int i = tid; i < 128 * C_OUT; i += 256) Wl[i] = Wf[base * C_OUT + i];
    __syncthreads();
    int node = blockIdx.x * 4 + (tid >> 6);
    if (node >= N_NODES) return;
    int lane = tid & 63;
    float acc[C_OUT];
#pragma unroll
    for (int o = 0; o < C_OUT; ++o) acc[o] = 0.f;
#pragma unroll
    for (int t = 0; t < 128; t += 64) {
        int c = t + lane;
        float v = h[(size_t)node * 128 + c];
#pragma unroll
        for (int o = 0; o < C_OUT; ++o) acc[o] += v * Wl[c * C_OUT + o];
    }
#pragma unroll
    for (int s = 32; s > 0; s >>= 1) {
#pragma unroll
        for (int o = 0; o < C_OUT; ++o) acc[o] += __shfl_down(acc[o], s, 64);
    }
    if (lane == 0) {
#pragma unroll
        for (int o = 0; o < C_OUT; ++o) {
            float r = acc[o] + (addBias ? bf[o] : out[(size_t)node * C_OUT + o]);
            out[(size_t)node * C_OUT + o] = r;
        }
    }
}

// ---------------- launch ----------------

extern "C" void kernel_launch(void* const* d_in, const int* in_sizes, int n_in,
                              void* d_out, int out_size, void* d_ws, size_t ws_size,
                              hipStream_t stream) {
    const float* x  = (const float*)d_in[0];
    const int*   ei = (const int*)d_in[1];   // [2,E] flat: [0:E)=row(src), [E:2E)=col(dst)
    const float* W1 = (const float*)d_in[2];
    const float* W2 = (const float*)d_in[4];
    const float* W3 = (const float*)d_in[6];
    // b1/b2/b3 (d_in[3,5,7]) absorbed exactly by BN mean-subtraction
    const float* g1  = (const float*)d_in[8];
    const float* be1 = (const float*)d_in[9];
    const float* g2  = (const float*)d_in[10];
    const float* be2 = (const float*)d_in[11];
    const float* g3  = (const float*)d_in[12];
    const float* be3 = (const float*)d_in[13];
    const float* Wf  = (const float*)d_in[14];
    const float* bf  = (const float*)d_in[15];
    float* out = (float*)d_out;

    char* ws = (char*)d_ws;
    size_t off = 0;
    auto alloc = [&](size_t bytes) -> void* {
        void* p = ws + off;
        off = (off + bytes + 255) & ~(size_t)255;
        return p;
    };
    int*   deg     = (int*)alloc((size_t)N_NODES * 4);
    int*   offsets = (int*)alloc((size_t)(N_NODES + 1) * 4);
    int*   cursor  = (int*)alloc((size_t)N_NODES * 4);
    int*   csr_src = (int*)alloc((size_t)(N_EDGES + N_NODES) * 4);
    float* dinv    = (float*)alloc((size_t)N_NODES * 4);
    float* sums    = (float*)alloc(768 * 4);
    float* sc      = (float*)alloc(128 * 4);
    float* sh      = (float*)alloc(128 * 4);
    float* hl      = (float*)alloc((size_t)N_NODES * 128 * 4);
    float* bufA    = (float*)alloc((size_t)N_NODES * 128 * 4);
    float* bufB    = (float*)alloc((size_t)N_NODES * 128 * 4);

    const int TPB = 256;
    // CSR build
    k_init<<<(N_NODES + TPB - 1) / TPB, TPB, 0, stream>>>(deg, sums);
    k_count<<<(N_EDGES + TPB - 1) / TPB, TPB, 0, stream>>>(ei + N_EDGES, deg);
    k_dinv<<<(N_NODES + TPB - 1) / TPB, TPB, 0, stream>>>(deg, dinv);
    k_scan<<<1, 1024, 0, stream>>>(deg, offsets, cursor);
    k_scatter<<<(N_EDGES + N_NODES + TPB - 1) / TPB, TPB, 0, stream>>>(ei, cursor, csr_src);

    const int gemm_grid = (N_NODES + 63) / 64;          // 782
    const int agg_grid  = (N_NODES + 3) / 4;            // wave per node, 4/block
    const int out_grid  = (N_NODES + 3) / 4;

    // ---- layer 1 ----
    k_gemm<<<gemm_grid, 256, 0, stream>>>(x, W1, hl);
    k_agg<<<agg_grid, 256, 0, stream>>>(hl, csr_src, offsets, dinv, bufA);
    k_bn_stats<<<512, 256, 0, stream>>>(bufA, sums + 0);
    k_bn_finalize<<<1, 128, 0, stream>>>(sums + 0, g1, be1, sc, sh);
    k_bn_apply<<<2048, 256, 0, stream>>>(bufA, sc, sh);
    k_out<<<out_grid, 256, 0, stream>>>(bufA, Wf, bf, out, 0, 1);

    // ---- layer 2 ----
    k_gemm<<<gemm_grid, 256, 0, stream>>>(bufA, W2, hl);
    k_agg<<<agg_grid, 256, 0, stream>>>(hl, csr_src, offsets, dinv, bufB);
    k_bn_stats<<<512, 256, 0, stream>>>(bufB, sums + 256);
    k_bn_finalize<<<1, 128, 0, stream>>>(sums + 256, g2, be2, sc, sh);
    k_bn_apply<<<2048, 256, 0, stream>>>(bufB, sc, sh);
    k_out<<<out_grid, 256, 0, stream>>>(bufB, Wf, bf, out, 128, 0);

    // ---- layer 3 ----
    k_gemm<<<gemm_grid, 256, 0, stream>>>(bufB, W3, hl);
    k_agg<<<agg_grid, 256, 0, stream>>>(hl, csr_src, offsets, dinv, bufA);
    k_bn_stats<<<512, 256, 0, stream>>>(bufA, sums + 512);
    k_bn_finalize<<<1, 128, 0, stream>>>(sums + 512, g3, be3, sc, sh);
    k_bn_apply<<<2048, 256, 0, stream>>>(bufA, sc, sh);
    k_out<<<out_grid, 256, 0, stream>>>(bufA, Wf, bf, out, 256, 0);
}

// Round 2
// 782.577 us; speedup vs baseline: 1.1032x; 1.1032x over previous
//
#include <hip/hip_runtime.h>

#define N_NODES 50000
#define N_EDGES 800000
#define D 128
#define C_OUT 10
#define BN_EPS 1e-5f

typedef unsigned int uint32;

__device__ __forceinline__ float bf2f(unsigned int u16) {
    unsigned int x = u16 << 16;
    float f;
    __builtin_memcpy(&f, &x, 4);
    return f;
}
__device__ __forceinline__ unsigned int f2bf(float f) {
    unsigned int x;
    __builtin_memcpy(&x, &f, 4);
    unsigned int r = x + 0x7FFFu + ((x >> 16) & 1u);  // RNE
    return r >> 16;
}
__device__ __forceinline__ uint32 pack_bf2(float a, float b) {
    return f2bf(a) | (f2bf(b) << 16);
}

// ---------------- CSR build ----------------

__global__ void k_init(int* deg, float* sums) {
    int i = blockIdx.x * blockDim.x + threadIdx.x;
    if (i < N_NODES) deg[i] = 1;          // self loop contributes 1 to in-degree
    if (i < 768) sums[i] = 0.0f;          // 3 layers x (sum[128] | sumsq[128])
}

__global__ void k_count(const int* __restrict__ col, int* __restrict__ deg) {
    int e = blockIdx.x * blockDim.x + threadIdx.x;
    if (e < N_EDGES) atomicAdd(&deg[col[e]], 1);
}

__global__ void k_dinv(const int* __restrict__ deg, float* __restrict__ dinv) {
    int i = blockIdx.x * blockDim.x + threadIdx.x;
    if (i < N_NODES) dinv[i] = rsqrtf((float)deg[i]);  // deg >= 1 always
}

// thread-serial chunks + one 1024-wide LDS scan (few barriers)
__global__ __launch_bounds__(1024) void k_scan(const int* __restrict__ deg,
                                               int* __restrict__ offsets,
                                               int* __restrict__ cursor) {
    __shared__ int sm[1024];
    const int CH = (N_NODES + 1023) / 1024;  // 49
    int tid = threadIdx.x;
    int b0 = tid * CH;
    int s = 0;
    for (int i = 0; i < CH; ++i) {
        int idx = b0 + i;
        if (idx < N_NODES) s += deg[idx];
    }
    sm[tid] = s;
    __syncthreads();
    for (int off = 1; off < 1024; off <<= 1) {
        int t = (tid >= off) ? sm[tid - off] : 0;
        __syncthreads();
        sm[tid] += t;
        __syncthreads();
    }
    int excl = sm[tid] - s;  // exclusive prefix of this thread's chunk
    if (tid == 1023) offsets[N_NODES] = sm[1023];
    for (int i = 0; i < CH; ++i) {
        int idx = b0 + i;
        if (idx < N_NODES) {
            offsets[idx] = excl;
            cursor[idx] = excl;
            excl += deg[idx];
        }
    }
}

__global__ void k_scatter(const int* __restrict__ ei, int* __restrict__ cursor,
                          int* __restrict__ csr_src) {
    int idx = blockIdx.x * blockDim.x + threadIdx.x;
    const int total = N_EDGES + N_NODES;
    if (idx >= total) return;
    int s, d;
    if (idx < N_EDGES) { s = ei[idx]; d = ei[N_EDGES + idx]; }  // row -> col
    else { s = idx - N_EDGES; d = s; }                           // self loop
    int p = atomicAdd(&cursor[d], 1);
    csr_src[p] = s;
}

// ---------------- GEMM: hl[M,128](bf16, pre-scaled by dinv) = bnrelu(A) @ W ----------------
// 64-row tile, K in 2 chunks of 64; optional fused BN+ReLU on A-load (sc/sh per column).

__global__ __launch_bounds__(256) void k_gemm(const float* __restrict__ A,
                                              const float* __restrict__ W,
                                              unsigned short* __restrict__ hl,
                                              const float* __restrict__ sc,
                                              const float* __restrict__ sh,
                                              const float* __restrict__ dinvp) {
    __shared__ float As[64 * 68];    // 64 rows x 64 k, pad stride 68
    __shared__ float Ws[64 * 128];   // 64 k x 128 cols
    int tid = threadIdx.x;
    int row0 = blockIdx.x * 64;

    const float4* A4 = (const float4*)A;
    const float4* W4 = (const float4*)W;
    float4* Ws4 = (float4*)Ws;
    const float4* sc4 = (const float4*)sc;
    const float4* sh4 = (const float4*)sh;

    int tc = (tid & 15) * 8;   // 16 col-groups of 8
    int tr = (tid >> 4) * 4;   // 16 row-groups of 4

    float acc[4][8];
#pragma unroll
    for (int i = 0; i < 4; ++i)
#pragma unroll
        for (int j = 0; j < 8; ++j) acc[i][j] = 0.f;

    for (int kc = 0; kc < 2; ++kc) {
#pragma unroll
        for (int it = 0; it < 8; ++it)
            Ws4[it * 256 + tid] = W4[kc * 2048 + it * 256 + tid];
#pragma unroll
        for (int it = 0; it < 4; ++it) {
            int f4 = it * 256 + tid;     // 0..1023
            int r = f4 >> 4;             // 16 float4 per row
            int c4 = f4 & 15;
            float4 v = make_float4(0.f, 0.f, 0.f, 0.f);
            int gr = row0 + r;
            if (gr < N_NODES) v = A4[(size_t)gr * 32 + kc * 16 + c4];
            if (sc) {  // fused BN + ReLU of previous layer
                float4 s = sc4[kc * 16 + c4];
                float4 t = sh4[kc * 16 + c4];
                v.x = fmaxf(v.x * s.x + t.x, 0.f);
                v.y = fmaxf(v.y * s.y + t.y, 0.f);
                v.z = fmaxf(v.z * s.z + t.z, 0.f);
                v.w = fmaxf(v.w * s.w + t.w, 0.f);
            }
            *(float4*)&As[r * 68 + c4 * 4] = v;
        }
        __syncthreads();
#pragma unroll 4
        for (int k = 0; k < 64; ++k) {
            float a[4] = {As[(tr + 0) * 68 + k], As[(tr + 1) * 68 + k],
                          As[(tr + 2) * 68 + k], As[(tr + 3) * 68 + k]};
            float4 b0 = *(float4*)&Ws[k * 128 + tc];
            float4 b1 = *(float4*)&Ws[k * 128 + tc + 4];
            float b[8] = {b0.x, b0.y, b0.z, b0.w, b1.x, b1.y, b1.z, b1.w};
#pragma unroll
            for (int i = 0; i < 4; ++i)
#pragma unroll
                for (int j = 0; j < 8; ++j) acc[i][j] += a[i] * b[j];
        }
        __syncthreads();
    }

#pragma unroll
    for (int i = 0; i < 4; ++i) {
        int r = row0 + tr + i;
        if (r < N_NODES) {
            float di = dinvp[r];  // pre-scale row by dinv[src]
            uint4 o;
            o.x = pack_bf2(acc[i][0] * di, acc[i][1] * di);
            o.y = pack_bf2(acc[i][2] * di, acc[i][3] * di);
            o.z = pack_bf2(acc[i][4] * di, acc[i][5] * di);
            o.w = pack_bf2(acc[i][6] * di, acc[i][7] * di);
            *(uint4*)&hl[(size_t)r * 128 + tc] = o;
        }
    }
}

// ---------------- Aggregation: one wave per node, 2 bf16/lane, unroll x2 ----------------

__global__ void k_agg(const unsigned short* __restrict__ hl, const int* __restrict__ csr_src,
                      const int* __restrict__ offsets, const float* __restrict__ dinv,
                      float* __restrict__ agg) {
    int wave = (int)((blockIdx.x * blockDim.x + threadIdx.x) >> 6);
    int lane = threadIdx.x & 63;
    if (wave >= N_NODES) return;
    int beg = offsets[wave], end = offsets[wave + 1];
    float ax = 0.f, ay = 0.f;
    int e = beg;
    for (; e + 1 < end; e += 2) {
        int j0 = csr_src[e];
        int j1 = csr_src[e + 1];
        uint32 p0 = *(const uint32*)&hl[(size_t)j0 * 128 + lane * 2];
        uint32 p1 = *(const uint32*)&hl[(size_t)j1 * 128 + lane * 2];
        ax += bf2f(p0 & 0xFFFFu) + bf2f(p1 & 0xFFFFu);
        ay += bf2f(p0 >> 16) + bf2f(p1 >> 16);
    }
    if (e < end) {
        int j = csr_src[e];
        uint32 p = *(const uint32*)&hl[(size_t)j * 128 + lane * 2];
        ax += bf2f(p & 0xFFFFu);
        ay += bf2f(p >> 16);
    }
    float di = dinv[wave];
    *(float2*)&agg[(size_t)wave * 128 + lane * 2] = make_float2(ax * di, ay * di);
}

// ---------------- BN ----------------

__global__ void k_bn_stats(const float* __restrict__ agg, float* __restrict__ sums) {
    __shared__ float sm[256];
    int tid = threadIdx.x;
    int c = tid & 127;
    float s = 0.f, q = 0.f;
    for (int r = blockIdx.x * 2 + (tid >> 7); r < N_NODES; r += gridDim.x * 2) {
        float v = agg[(size_t)r * 128 + c];
        s += v;
        q += v * v;
    }
    sm[tid] = s;
    __syncthreads();
    if (tid < 128) atomicAdd(&sums[c], sm[tid] + sm[tid + 128]);
    __syncthreads();
    sm[tid] = q;
    __syncthreads();
    if (tid < 128) atomicAdd(&sums[128 + c], sm[tid] + sm[tid + 128]);
}

__global__ void k_bn_finalize(const float* __restrict__ sums, const float* __restrict__ g,
                              const float* __restrict__ be, float* __restrict__ sc,
                              float* __restrict__ sh) {
    int c = threadIdx.x;
    if (c < 128) {
        float mean = sums[c] / (float)N_NODES;
        float var = sums[128 + c] / (float)N_NODES - mean * mean;
        var = fmaxf(var, 0.f);
        float s = g[c] * rsqrtf(var + BN_EPS);
        sc[c] = s;
        sh[c] = be[c] - mean * s;
    }
}

// ---------------- Final readout: out (+)= bnrelu(h) @ Wf[base:base+128, :] ----------------

__global__ void k_out(const float* __restrict__ h, const float* __restrict__ Wf,
                      const float* __restrict__ bf, float* __restrict__ out,
                      int base, int addBias, const float* __restrict__ sc,
                      const float* __restrict__ sh) {
    __shared__ float Wl[128 * C_OUT];  // 5KB slice
    __shared__ float scl[128], shl[128];
    int tid = threadIdx.x;
    for (int i = tid; i < 128 * C_OUT; i += 256) Wl[i] = Wf[base * C_OUT + i];
    if (tid < 128) { scl[tid] = sc[tid]; shl[tid] = sh[tid]; }
    __syncthreads();
    int node = blockIdx.x * 4 + (tid >> 6);
    if (node >= N_NODES) return;
    int lane = tid & 63;
    float acc[C_OUT];
#pragma unroll
    for (int o = 0; o < C_OUT; ++o) acc[o] = 0.f;
#pragma unroll
    for (int t = 0; t < 128; t += 64) {
        int c = t + lane;
        float v = h[(size_t)node * 128 + c];
        v = fmaxf(v * scl[c] + shl[c], 0.f);  // fused BN + ReLU
#pragma unroll
        for (int o = 0; o < C_OUT; ++o) acc[o] += v * Wl[c * C_OUT + o];
    }
#pragma unroll
    for (int s = 32; s > 0; s >>= 1) {
#pragma unroll
        for (int o = 0; o < C_OUT; ++o) acc[o] += __shfl_down(acc[o], s, 64);
    }
    if (lane == 0) {
#pragma unroll
        for (int o = 0; o < C_OUT; ++o) {
            float r = acc[o] + (addBias ? bf[o] : out[(size_t)node * C_OUT + o]);
            out[(size_t)node * C_OUT + o] = r;
        }
    }
}

// ---------------- launch ----------------

extern "C" void kernel_launch(void* const* d_in, const int* in_sizes, int n_in,
                              void* d_out, int out_size, void* d_ws, size_t ws_size,
                              hipStream_t stream) {
    const float* x  = (const float*)d_in[0];
    const int*   ei = (const int*)d_in[1];   // [2,E] flat: [0:E)=row(src), [E:2E)=col(dst)
    const float* W1 = (const float*)d_in[2];
    const float* W2 = (const float*)d_in[4];
    const float* W3 = (const float*)d_in[6];
    // b1/b2/b3 (d_in[3,5,7]) absorbed exactly by BN mean-subtraction
    const float* g1  = (const float*)d_in[8];
    const float* be1 = (const float*)d_in[9];
    const float* g2  = (const float*)d_in[10];
    const float* be2 = (const float*)d_in[11];
    const float* g3  = (const float*)d_in[12];
    const float* be3 = (const float*)d_in[13];
    const float* Wf  = (const float*)d_in[14];
    const float* bf  = (const float*)d_in[15];
    float* out = (float*)d_out;

    char* ws = (char*)d_ws;
    size_t off = 0;
    auto alloc = [&](size_t bytes) -> void* {
        void* p = ws + off;
        off = (off + bytes + 255) & ~(size_t)255;
        return p;
    };
    int*   deg     = (int*)alloc((size_t)N_NODES * 4);
    int*   offsets = (int*)alloc((size_t)(N_NODES + 1) * 4);
    int*   cursor  = (int*)alloc((size_t)N_NODES * 4);
    int*   csr_src = (int*)alloc((size_t)(N_EDGES + N_NODES) * 4);
    float* dinv    = (float*)alloc((size_t)N_NODES * 4);
    float* sums    = (float*)alloc(768 * 4);
    float* sc1 = (float*)alloc(128 * 4);  float* sh1 = (float*)alloc(128 * 4);
    float* sc2 = (float*)alloc(128 * 4);  float* sh2 = (float*)alloc(128 * 4);
    float* sc3 = (float*)alloc(128 * 4);  float* sh3 = (float*)alloc(128 * 4);
    unsigned short* hl = (unsigned short*)alloc((size_t)N_NODES * 128 * 2);  // bf16
    float* bufA    = (float*)alloc((size_t)N_NODES * 128 * 4);
    float* bufB    = (float*)alloc((size_t)N_NODES * 128 * 4);

    const int TPB = 256;
    // CSR build
    k_init<<<(N_NODES + TPB - 1) / TPB, TPB, 0, stream>>>(deg, sums);
    k_count<<<(N_EDGES + TPB - 1) / TPB, TPB, 0, stream>>>(ei + N_EDGES, deg);
    k_dinv<<<(N_NODES + TPB - 1) / TPB, TPB, 0, stream>>>(deg, dinv);
    k_scan<<<1, 1024, 0, stream>>>(deg, offsets, cursor);
    k_scatter<<<(N_EDGES + N_NODES + TPB - 1) / TPB, TPB, 0, stream>>>(ei, cursor, csr_src);

    const int gemm_grid = (N_NODES + 63) / 64;          // 782
    const int agg_grid  = (N_NODES + 3) / 4;            // wave per node, 4/block
    const int out_grid  = (N_NODES + 3) / 4;

    // ---- layer 1 ----
    k_gemm<<<gemm_grid, 256, 0, stream>>>(x, W1, hl, nullptr, nullptr, dinv);
    k_agg<<<agg_grid, 256, 0, stream>>>(hl, csr_src, offsets, dinv, bufA);
    k_bn_stats<<<512, 256, 0, stream>>>(bufA, sums + 0);
    k_bn_finalize<<<1, 128, 0, stream>>>(sums + 0, g1, be1, sc1, sh1);
    k_out<<<out_grid, 256, 0, stream>>>(bufA, Wf, bf, out, 0, 1, sc1, sh1);

    // ---- layer 2 ----
    k_gemm<<<gemm_grid, 256, 0, stream>>>(bufA, W2, hl, sc1, sh1, dinv);
    k_agg<<<agg_grid, 256, 0, stream>>>(hl, csr_src, offsets, dinv, bufB);
    k_bn_stats<<<512, 256, 0, stream>>>(bufB, sums + 256);
    k_bn_finalize<<<1, 128, 0, stream>>>(sums + 256, g2, be2, sc2, sh2);
    k_out<<<out_grid, 256, 0, stream>>>(bufB, Wf, bf, out, 128, 0, sc2, sh2);

    // ---- layer 3 ----
    k_gemm<<<gemm_grid, 256, 0, stream>>>(bufB, W3, hl, sc2, sh2, dinv);
    k_agg<<<agg_grid, 256, 0, stream>>>(hl, csr_src, offsets, dinv, bufA);
    k_bn_stats<<<512, 256, 0, stream>>>(bufA, sums + 512);
    k_bn_finalize<<<1, 128, 0, stream>>>(sums + 512, g3, be3, sc3, sh3);
    k_out<<<out_grid, 256, 0, stream>>>(bufA, Wf, bf, out, 256, 0, sc3, sh3);
}

// Round 3
// 665.138 us; speedup vs baseline: 1.2980x; 1.1766x over previous
//
#include <hip/hip_runtime.h>

#define N_NODES 50000
#define N_EDGES 800000
#define D 128
#define C_OUT 10
#define BN_EPS 1e-5f
#define SCAN_BLOCKS 196   // ceil(50000/256)

typedef unsigned int uint32;

__device__ __forceinline__ float bf2f(unsigned int u16) {
    unsigned int x = u16 << 16;
    float f;
    __builtin_memcpy(&f, &x, 4);
    return f;
}
__device__ __forceinline__ unsigned int f2bf(float f) {
    unsigned int x;
    __builtin_memcpy(&x, &f, 4);
    unsigned int r = x + 0x7FFFu + ((x >> 16) & 1u);  // RNE
    return r >> 16;
}
__device__ __forceinline__ uint32 pack_bf2(float a, float b) {
    return f2bf(a) | (f2bf(b) << 16);
}

// ---------------- CSR build ----------------

__global__ void k_init(int* deg, float* sums) {
    int i = blockIdx.x * blockDim.x + threadIdx.x;
    if (i < N_NODES) deg[i] = 1;          // self loop contributes 1 to in-degree
    if (i < 768) sums[i] = 0.0f;          // 3 layers x (sum[128] | sumsq[128])
}

__global__ void k_count(const int* __restrict__ col, int* __restrict__ deg) {
    int e = blockIdx.x * blockDim.x + threadIdx.x;
    if (e < N_EDGES) atomicAdd(&deg[col[e]], 1);
}

// scan stage 1: per-block local exclusive prefix + block totals; fold dinv in.
__global__ __launch_bounds__(256) void k_scan1(const int* __restrict__ deg,
                                               int* __restrict__ offsets,
                                               int* __restrict__ blocksum,
                                               float* __restrict__ dinv) {
    __shared__ int sm[256];
    int tid = threadIdx.x;
    int i = blockIdx.x * 256 + tid;
    int v = (i < N_NODES) ? deg[i] : 0;
    if (i < N_NODES) dinv[i] = rsqrtf((float)v);  // deg >= 1 always
    sm[tid] = v;
    __syncthreads();
    for (int off = 1; off < 256; off <<= 1) {
        int t = (tid >= off) ? sm[tid - off] : 0;
        __syncthreads();
        sm[tid] += t;
        __syncthreads();
    }
    if (i < N_NODES) offsets[i] = sm[tid] - v;  // local exclusive prefix
    if (tid == 255) blocksum[blockIdx.x] = sm[255];
}

// scan stage 2: single block scans SCAN_BLOCKS totals -> exclusive block offsets
__global__ __launch_bounds__(256) void k_scan2(int* __restrict__ blocksum,
                                               int* __restrict__ offsets) {
    __shared__ int sm[256];
    int tid = threadIdx.x;
    int v = (tid < SCAN_BLOCKS) ? blocksum[tid] : 0;
    sm[tid] = v;
    __syncthreads();
    for (int off = 1; off < 256; off <<= 1) {
        int t = (tid >= off) ? sm[tid - off] : 0;
        __syncthreads();
        sm[tid] += t;
        __syncthreads();
    }
    if (tid < SCAN_BLOCKS) blocksum[tid] = sm[tid] - v;  // exclusive
    if (tid == 255) offsets[N_NODES] = sm[255];          // total = E + N
}

// scan stage 3: add block offset, write cursor
__global__ __launch_bounds__(256) void k_scan3(int* __restrict__ offsets,
                                               const int* __restrict__ blocksum,
                                               int* __restrict__ cursor) {
    int i = blockIdx.x * 256 + threadIdx.x;
    if (i < N_NODES) {
        int o = offsets[i] + blocksum[blockIdx.x];
        offsets[i] = o;
        cursor[i] = o;
    }
}

__global__ void k_scatter(const int* __restrict__ ei, int* __restrict__ cursor,
                          int* __restrict__ csr_src) {
    int idx = blockIdx.x * blockDim.x + threadIdx.x;
    const int total = N_EDGES + N_NODES;
    if (idx >= total) return;
    int s, d;
    if (idx < N_EDGES) { s = ei[idx]; d = ei[N_EDGES + idx]; }  // row -> col
    else { s = idx - N_EDGES; d = s; }                           // self loop
    int p = atomicAdd(&cursor[d], 1);
    csr_src[p] = s;
}

// ---------------- GEMM: hl[M,128](bf16, pre-scaled by dinv) = bnrelu(A) @ W ----------------

__global__ __launch_bounds__(256) void k_gemm(const float* __restrict__ A,
                                              const float* __restrict__ W,
                                              unsigned short* __restrict__ hl,
                                              const float* __restrict__ sc,
                                              const float* __restrict__ sh,
                                              const float* __restrict__ dinvp) {
    __shared__ float As[64 * 68];    // 64 rows x 64 k, pad stride 68
    __shared__ float Ws[64 * 128];   // 64 k x 128 cols
    int tid = threadIdx.x;
    int row0 = blockIdx.x * 64;

    const float4* A4 = (const float4*)A;
    const float4* W4 = (const float4*)W;
    float4* Ws4 = (float4*)Ws;
    const float4* sc4 = (const float4*)sc;
    const float4* sh4 = (const float4*)sh;

    int tc = (tid & 15) * 8;   // 16 col-groups of 8
    int tr = (tid >> 4) * 4;   // 16 row-groups of 4

    float acc[4][8];
#pragma unroll
    for (int i = 0; i < 4; ++i)
#pragma unroll
        for (int j = 0; j < 8; ++j) acc[i][j] = 0.f;

    for (int kc = 0; kc < 2; ++kc) {
#pragma unroll
        for (int it = 0; it < 8; ++it)
            Ws4[it * 256 + tid] = W4[kc * 2048 + it * 256 + tid];
#pragma unroll
        for (int it = 0; it < 4; ++it) {
            int f4 = it * 256 + tid;     // 0..1023
            int r = f4 >> 4;             // 16 float4 per row
            int c4 = f4 & 15;
            float4 v = make_float4(0.f, 0.f, 0.f, 0.f);
            int gr = row0 + r;
            if (gr < N_NODES) v = A4[(size_t)gr * 32 + kc * 16 + c4];
            if (sc) {  // fused BN + ReLU of previous layer
                float4 s = sc4[kc * 16 + c4];
                float4 t = sh4[kc * 16 + c4];
                v.x = fmaxf(v.x * s.x + t.x, 0.f);
                v.y = fmaxf(v.y * s.y + t.y, 0.f);
                v.z = fmaxf(v.z * s.z + t.z, 0.f);
                v.w = fmaxf(v.w * s.w + t.w, 0.f);
            }
            *(float4*)&As[r * 68 + c4 * 4] = v;
        }
        __syncthreads();
#pragma unroll 4
        for (int k = 0; k < 64; ++k) {
            float a[4] = {As[(tr + 0) * 68 + k], As[(tr + 1) * 68 + k],
                          As[(tr + 2) * 68 + k], As[(tr + 3) * 68 + k]};
            float4 b0 = *(float4*)&Ws[k * 128 + tc];
            float4 b1 = *(float4*)&Ws[k * 128 + tc + 4];
            float b[8] = {b0.x, b0.y, b0.z, b0.w, b1.x, b1.y, b1.z, b1.w};
#pragma unroll
            for (int i = 0; i < 4; ++i)
#pragma unroll
                for (int j = 0; j < 8; ++j) acc[i][j] += a[i] * b[j];
        }
        __syncthreads();
    }

#pragma unroll
    for (int i = 0; i < 4; ++i) {
        int r = row0 + tr + i;
        if (r < N_NODES) {
            float di = dinvp[r];  // pre-scale row by dinv[src]
            uint4 o;
            o.x = pack_bf2(acc[i][0] * di, acc[i][1] * di);
            o.y = pack_bf2(acc[i][2] * di, acc[i][3] * di);
            o.z = pack_bf2(acc[i][4] * di, acc[i][5] * di);
            o.w = pack_bf2(acc[i][6] * di, acc[i][7] * di);
            *(uint4*)&hl[(size_t)r * 128 + tc] = o;
        }
    }
}

// ---------------- Aggregation: one wave per node, 2 bf16/lane, unroll x2 ----------------

__global__ void k_agg(const unsigned short* __restrict__ hl, const int* __restrict__ csr_src,
                      const int* __restrict__ offsets, const float* __restrict__ dinv,
                      float* __restrict__ agg) {
    int wave = (int)((blockIdx.x * blockDim.x + threadIdx.x) >> 6);
    int lane = threadIdx.x & 63;
    if (wave >= N_NODES) return;
    int beg = offsets[wave], end = offsets[wave + 1];
    float ax = 0.f, ay = 0.f;
    int e = beg;
    for (; e + 1 < end; e += 2) {
        int j0 = csr_src[e];
        int j1 = csr_src[e + 1];
        uint32 p0 = *(const uint32*)&hl[(size_t)j0 * 128 + lane * 2];
        uint32 p1 = *(const uint32*)&hl[(size_t)j1 * 128 + lane * 2];
        ax += bf2f(p0 & 0xFFFFu) + bf2f(p1 & 0xFFFFu);
        ay += bf2f(p0 >> 16) + bf2f(p1 >> 16);
    }
    if (e < end) {
        int j = csr_src[e];
        uint32 p = *(const uint32*)&hl[(size_t)j * 128 + lane * 2];
        ax += bf2f(p & 0xFFFFu);
        ay += bf2f(p >> 16);
    }
    float di = dinv[wave];
    *(float2*)&agg[(size_t)wave * 128 + lane * 2] = make_float2(ax * di, ay * di);
}

// ---------------- BN ----------------

__global__ void k_bn_stats(const float* __restrict__ agg, float* __restrict__ sums) {
    __shared__ float sm[256];
    int tid = threadIdx.x;
    int c = tid & 127;
    float s = 0.f, q = 0.f;
    for (int r = blockIdx.x * 2 + (tid >> 7); r < N_NODES; r += gridDim.x * 2) {
        float v = agg[(size_t)r * 128 + c];
        s += v;
        q += v * v;
    }
    sm[tid] = s;
    __syncthreads();
    if (tid < 128) atomicAdd(&sums[c], sm[tid] + sm[tid + 128]);
    __syncthreads();
    sm[tid] = q;
    __syncthreads();
    if (tid < 128) atomicAdd(&sums[128 + c], sm[tid] + sm[tid + 128]);
}

__global__ void k_bn_finalize(const float* __restrict__ sums, const float* __restrict__ g,
                              const float* __restrict__ be, float* __restrict__ sc,
                              float* __restrict__ sh) {
    int c = threadIdx.x;
    if (c < 128) {
        float mean = sums[c] / (float)N_NODES;
        float var = sums[128 + c] / (float)N_NODES - mean * mean;
        var = fmaxf(var, 0.f);
        float s = g[c] * rsqrtf(var + BN_EPS);
        sc[c] = s;
        sh[c] = be[c] - mean * s;
    }
}

// ---------------- Final readout: out (+)= bnrelu(h) @ Wf[base:base+128, :] ----------------

__global__ void k_out(const float* __restrict__ h, const float* __restrict__ Wf,
                      const float* __restrict__ bf, float* __restrict__ out,
                      int base, int addBias, const float* __restrict__ sc,
                      const float* __restrict__ sh) {
    __shared__ float Wl[128 * C_OUT];  // 5KB slice
    __shared__ float scl[128], shl[128];
    int tid = threadIdx.x;
    for (int i = tid; i < 128 * C_OUT; i += 256) Wl[i] = Wf[base * C_OUT + i];
    if (tid < 128) { scl[tid] = sc[tid]; shl[tid] = sh[tid]; }
    __syncthreads();
    int node = blockIdx.x * 4 + (tid >> 6);
    if (node >= N_NODES) return;
    int lane = tid & 63;
    float acc[C_OUT];
#pragma unroll
    for (int o = 0; o < C_OUT; ++o) acc[o] = 0.f;
#pragma unroll
    for (int t = 0; t < 128; t += 64) {
        int c = t + lane;
        float v = h[(size_t)node * 128 + c];
        v = fmaxf(v * scl[c] + shl[c], 0.f);  // fused BN + ReLU
#pragma unroll
        for (int o = 0; o < C_OUT; ++o) acc[o] += v * Wl[c * C_OUT + o];
    }
#pragma unroll
    for (int s = 32; s > 0; s >>= 1) {
#pragma unroll
        for (int o = 0; o < C_OUT; ++o) acc[o] += __shfl_down(acc[o], s, 64);
    }
    if (lane == 0) {
#pragma unroll
        for (int o = 0; o < C_OUT; ++o) {
            float r = acc[o] + (addBias ? bf[o] : out[(size_t)node * C_OUT + o]);
            out[(size_t)node * C_OUT + o] = r;
        }
    }
}

// ---------------- launch ----------------

extern "C" void kernel_launch(void* const* d_in, const int* in_sizes, int n_in,
                              void* d_out, int out_size, void* d_ws, size_t ws_size,
                              hipStream_t stream) {
    const float* x  = (const float*)d_in[0];
    const int*   ei = (const int*)d_in[1];   // [2,E] flat: [0:E)=row(src), [E:2E)=col(dst)
    const float* W1 = (const float*)d_in[2];
    const float* W2 = (const float*)d_in[4];
    const float* W3 = (const float*)d_in[6];
    // b1/b2/b3 (d_in[3,5,7]) absorbed exactly by BN mean-subtraction
    const float* g1  = (const float*)d_in[8];
    const float* be1 = (const float*)d_in[9];
    const float* g2  = (const float*)d_in[10];
    const float* be2 = (const float*)d_in[11];
    const float* g3  = (const float*)d_in[12];
    const float* be3 = (const float*)d_in[13];
    const float* Wf  = (const float*)d_in[14];
    const float* bf  = (const float*)d_in[15];
    float* out = (float*)d_out;

    char* ws = (char*)d_ws;
    size_t off = 0;
    auto alloc = [&](size_t bytes) -> void* {
        void* p = ws + off;
        off = (off + bytes + 255) & ~(size_t)255;
        return p;
    };
    int*   deg      = (int*)alloc((size_t)N_NODES * 4);
    int*   offsets  = (int*)alloc((size_t)(N_NODES + 1) * 4);
    int*   cursor   = (int*)alloc((size_t)N_NODES * 4);
    int*   blocksum = (int*)alloc((size_t)SCAN_BLOCKS * 4);
    int*   csr_src  = (int*)alloc((size_t)(N_EDGES + N_NODES) * 4);
    float* dinv     = (float*)alloc((size_t)N_NODES * 4);
    float* sums     = (float*)alloc(768 * 4);
    float* sc1 = (float*)alloc(128 * 4);  float* sh1 = (float*)alloc(128 * 4);
    float* sc2 = (float*)alloc(128 * 4);  float* sh2 = (float*)alloc(128 * 4);
    float* sc3 = (float*)alloc(128 * 4);  float* sh3 = (float*)alloc(128 * 4);
    unsigned short* hl = (unsigned short*)alloc((size_t)N_NODES * 128 * 2);  // bf16
    float* bufA    = (float*)alloc((size_t)N_NODES * 128 * 4);
    float* bufB    = (float*)alloc((size_t)N_NODES * 128 * 4);

    const int TPB = 256;
    // CSR build
    k_init<<<(N_NODES + TPB - 1) / TPB, TPB, 0, stream>>>(deg, sums);
    k_count<<<(N_EDGES + TPB - 1) / TPB, TPB, 0, stream>>>(ei + N_EDGES, deg);
    k_scan1<<<SCAN_BLOCKS, 256, 0, stream>>>(deg, offsets, blocksum, dinv);
    k_scan2<<<1, 256, 0, stream>>>(blocksum, offsets);
    k_scan3<<<SCAN_BLOCKS, 256, 0, stream>>>(offsets, blocksum, cursor);
    k_scatter<<<(N_EDGES + N_NODES + TPB - 1) / TPB, TPB, 0, stream>>>(ei, cursor, csr_src);

    const int gemm_grid = (N_NODES + 63) / 64;          // 782
    const int agg_grid  = (N_NODES + 3) / 4;            // wave per node, 4/block
    const int out_grid  = (N_NODES + 3) / 4;

    // ---- layer 1 ----
    k_gemm<<<gemm_grid, 256, 0, stream>>>(x, W1, hl, nullptr, nullptr, dinv);
    k_agg<<<agg_grid, 256, 0, stream>>>(hl, csr_src, offsets, dinv, bufA);
    k_bn_stats<<<512, 256, 0, stream>>>(bufA, sums + 0);
    k_bn_finalize<<<1, 128, 0, stream>>>(sums + 0, g1, be1, sc1, sh1);
    k_out<<<out_grid, 256, 0, stream>>>(bufA, Wf, bf, out, 0, 1, sc1, sh1);

    // ---- layer 2 ----
    k_gemm<<<gemm_grid, 256, 0, stream>>>(bufA, W2, hl, sc1, sh1, dinv);
    k_agg<<<agg_grid, 256, 0, stream>>>(hl, csr_src, offsets, dinv, bufB);
    k_bn_stats<<<512, 256, 0, stream>>>(bufB, sums + 256);
    k_bn_finalize<<<1, 128, 0, stream>>>(sums + 256, g2, be2, sc2, sh2);
    k_out<<<out_grid, 256, 0, stream>>>(bufB, Wf, bf, out, 128, 0, sc2, sh2);

    // ---- layer 3 ----
    k_gemm<<<gemm_grid, 256, 0, stream>>>(bufB, W3, hl, sc2, sh2, dinv);
    k_agg<<<agg_grid, 256, 0, stream>>>(hl, csr_src, offsets, dinv, bufA);
    k_bn_stats<<<512, 256, 0, stream>>>(bufA, sums + 512);
    k_bn_finalize<<<1, 128, 0, stream>>>(sums + 512, g3, be3, sc3, sh3);
    k_out<<<out_grid, 256, 0, stream>>>(bufA, Wf, bf, out, 256, 0, sc3, sh3);
}